// Round 3
// baseline (95.670 us; speedup 1.0000x reference)
//
#include <hip/hip_runtime.h>

#define T_N 256
#define O_N 64
#define K_N 16
#define HW_N (224 * 224)      // 50176
#define DM 768
#define DO 2048
#define OMEGA_F 1e-6f

#define PCOLS 64
#define PSEG 4
#define PDSEG (DM / PSEG)     // 192
#define NB_PROJ_O (DO / PCOLS)            // 32
#define NB_PROJ_F (DM / PCOLS)            // 12
#define NB_PROJ (NB_PROJ_O + NB_PROJ_F)   // 44
#define SUBB 4
#define NB_HIST (T_N * SUBB)              // 1024

// ============ Kernel A: fused projections (blocks 0..43) + histogram (blocks 44..1067)
// LDS union: proj needs 4*16*64*4 = 16384 B; hist needs 256*17*4 + 16*17*4 = 18496 B.
__global__ __launch_bounds__(256) void fusedA(const float* __restrict__ me,
                                              const float* __restrict__ Wo, const float* __restrict__ bo,
                                              const float* __restrict__ Wf, const float* __restrict__ bf,
                                              const int* __restrict__ masks,
                                              float* __restrict__ proj_obj, float* __restrict__ proj_frame,
                                              float* __restrict__ counts_partial) {
    __shared__ char smem[18496];
    const int b = blockIdx.x;
    const int tid = threadIdx.x;

    if (b < NB_PROJ) {
        // ---- projection tile: 64 output cols x 16 k-rows, 4 K-segments of 192
        float (*partial)[K_N][PCOLS] = (float (*)[K_N][PCOLS])smem;
        const float* W; const float* bias; float* out; int ld; int j0;
        if (b < NB_PROJ_O) { W = Wo; bias = bo; out = proj_obj;   ld = DO; j0 = b * PCOLS; }
        else               { W = Wf; bias = bf; out = proj_frame; ld = DM; j0 = (b - NB_PROJ_O) * PCOLS; }

        const int jj = tid & (PCOLS - 1);
        const int s  = tid >> 6;               // 0..3 (wave-uniform)
        const int j  = j0 + jj;

        float acc[K_N];
        #pragma unroll
        for (int k = 0; k < K_N; ++k) acc[k] = 0.f;

        const int d0 = s * PDSEG;
        #pragma unroll 4
        for (int d = d0; d < d0 + PDSEG; ++d) {
            float w = W[(size_t)d * ld + j];         // coalesced across 64 lanes
            #pragma unroll
            for (int k = 0; k < K_N; ++k)
                acc[k] += me[k * DM + d] * w;        // wave-uniform -> scalar loads, L2-hot
        }
        #pragma unroll
        for (int k = 0; k < K_N; ++k) partial[s][k][jj] = acc[k];
        __syncthreads();

        for (int o = tid; o < K_N * PCOLS; o += 256) {
            int k = o >> 6, c = o & 63;
            float ssum = 0.f;
            #pragma unroll
            for (int s2 = 0; s2 < PSEG; ++s2) ssum += partial[s2][k][c];
            out[k * ld + j0 + c] = ssum + bias[j0 + c];
        }
    } else {
        // ---- histogram: per-thread private bins, 4 sub-blocks per frame
        int* bins = (int*)smem;                              // 256*17 ints
        int (*partial2)[17] = (int (*)[17])(smem + 256 * 17 * 4);
        const int hb = b - NB_PROJ;
        const int t = hb >> 2, sub = hb & 3;
        int* my = &bins[tid * 17];
        #pragma unroll
        for (int i = 0; i < 17; ++i) my[i] = 0;

        const int4* p = (const int4*)(masks + (size_t)t * HW_N);
        const int n4 = HW_N / 4;          // 12544
        const int chunk = n4 / SUBB;      // 3136
        const int end = (sub + 1) * chunk;
        for (int i = sub * chunk + tid; i < end; i += 256) {
            int4 v = p[i];
            my[v.x]++; my[v.y]++; my[v.z]++; my[v.w]++;
        }
        __syncthreads();
        const int bcol = tid & 15, rg = tid >> 4;
        int ssum = 0;
        #pragma unroll
        for (int r = 0; r < 16; ++r) ssum += bins[(rg * 16 + r) * 17 + (bcol + 1)];
        partial2[rg][bcol] = ssum;
        __syncthreads();
        if (tid < 16) {
            int s = 0;
            #pragma unroll
            for (int r = 0; r < 16; ++r) s += partial2[r][tid];
            counts_partial[((size_t)sub * T_N + t) * K_N + tid] = (float)s;
        }
    }
}

// ============ Kernel B: fused frame injection (blocks 0..255) + obj injection (blocks 256..16639)
__global__ __launch_bounds__(256) void fusedB(const float* __restrict__ obj_feat,
                                              const int* __restrict__ obj_entity,
                                              const float* __restrict__ proj_obj,
                                              const float* __restrict__ frame_feat,
                                              const float* __restrict__ counts_partial,
                                              const float* __restrict__ proj_frame,
                                              const float* __restrict__ gamma,
                                              float* __restrict__ obj_out,
                                              float* __restrict__ frame_out) {
    __shared__ float c[K_N];
    const int b = blockIdx.x;
    const float g = gamma[0];

    if (b < T_N) {
        // ---- frame: one block per frame t
        const int t = b;
        if (threadIdx.x < K_N) {
            float s = 0.f;
            #pragma unroll
            for (int sb = 0; sb < SUBB; ++sb)
                s += counts_partial[((size_t)sb * T_N + t) * K_N + threadIdx.x];
            c[threadIdx.x] = s;
        }
        __syncthreads();
        float tot = 0.f;
        #pragma unroll
        for (int k = 0; k < K_N; ++k) tot += c[k];
        const float inv = g / (OMEGA_F + tot);
        for (int j = threadIdx.x; j < DM; j += 256) {
            float acc = 0.f;
            #pragma unroll
            for (int k = 0; k < K_N; ++k) acc += c[k] * proj_frame[k * DM + j];
            frame_out[t * DM + j] = frame_feat[t * DM + j] + acc * inv;
        }
    } else {
        // ---- obj: one block per (t,o) row of 2048 floats
        const int row = b - T_N;
        const int e = obj_entity[row];              // scalar broadcast
        const float4* src = (const float4*)(obj_feat + (size_t)row * DO);
        float4* dst = (float4*)(obj_out + (size_t)row * DO);
        const int n4 = DO / 4;                      // 512
        if (e > 0) {
            const float4* pr = (const float4*)(proj_obj + (size_t)(e - 1) * DO);
            for (int i = threadIdx.x; i < n4; i += 256) {
                float4 a = src[i];
                float4 p = pr[i];
                dst[i] = make_float4(a.x + g * p.x, a.y + g * p.y,
                                     a.z + g * p.z, a.w + g * p.w);
            }
        } else {
            for (int i = threadIdx.x; i < n4; i += 256) dst[i] = src[i];
        }
    }
}

extern "C" void kernel_launch(void* const* d_in, const int* in_sizes, int n_in,
                              void* d_out, int out_size, void* d_ws, size_t ws_size,
                              hipStream_t stream) {
    const float* obj_feat   = (const float*)d_in[0];   // [T,O,DO]
    const float* frame_feat = (const float*)d_in[1];   // [T,DM]
    const float* me         = (const float*)d_in[2];   // [K,DM]
    const int*   obj_entity = (const int*)d_in[3];     // [T,O]
    const int*   masks      = (const int*)d_in[4];     // [T,H,W]
    const float* Wo         = (const float*)d_in[5];   // [DM,DO]
    const float* bo         = (const float*)d_in[6];   // [DO]
    const float* Wf         = (const float*)d_in[7];   // [DM,DM]
    const float* bf         = (const float*)d_in[8];   // [DM]
    const float* gamma      = (const float*)d_in[9];   // scalar

    float* obj_out   = (float*)d_out;                          // [T,O,DO]
    float* frame_out = (float*)d_out + (size_t)T_N * O_N * DO; // [T,DM]

    float* ws = (float*)d_ws;
    float* proj_obj       = ws;                  // 16*2048 = 32768 floats
    float* proj_frame     = ws + 32768;          // 16*768  = 12288 floats
    float* counts_partial = ws + 32768 + 12288;  // 4*256*16 = 16384 floats

    fusedA<<<NB_PROJ + NB_HIST, 256, 0, stream>>>(
        me, Wo, bo, Wf, bf, masks, proj_obj, proj_frame, counts_partial);
    fusedB<<<T_N + T_N * O_N, 256, 0, stream>>>(
        obj_feat, obj_entity, proj_obj, frame_feat, counts_partial, proj_frame,
        gamma, obj_out, frame_out);
}

// Round 4
// 77.852 us; speedup vs baseline: 1.2289x; 1.2289x over previous
//
#include <hip/hip_runtime.h>

#define T_N 256
#define O_N 64
#define K_N 16
#define HW_N (224 * 224)      // 50176
#define DM 768
#define DO 2048
#define OMEGA_F 1e-6f

// ---- proj decomposition: column-tiles x K-segments, atomic split-K ----
#define PCOLS 64
#define DSEG 64                     // d's per proj block
#define NSEG (DM / DSEG)            // 12
#define NT_O (DO / PCOLS)           // 32 col-tiles (obj proj)
#define NT_F (DM / PCOLS)           // 12 col-tiles (frame proj)
#define NB_PROJ ((NT_O + NT_F) * NSEG)   // 528
#define SUBB 4
#define NB_HIST (T_N * SUBB)        // 1024

// ============ Kernel A: proj blocks [0..527] + histogram blocks [528..1551]
// LDS union: proj = 4*16*64*4 (partial) + 16*64*4 (me slice) = 20480 B
//            hist = 256*17*4 + 16*17*4 = 18496 B  -> 20480 B, 8 blocks/CU.
__global__ __launch_bounds__(256) void fusedA(const float* __restrict__ me,
                                              const float* __restrict__ Wo, const float* __restrict__ bo,
                                              const float* __restrict__ Wf, const float* __restrict__ bf,
                                              const int* __restrict__ masks,
                                              float* __restrict__ proj_obj, float* __restrict__ proj_frame,
                                              float* __restrict__ counts_partial) {
    __shared__ char smem[20480];
    const int b = blockIdx.x;
    const int tid = threadIdx.x;

    if (b < NB_PROJ) {
        // ---- one 64-col x 64-d partial GEMM tile, atomically accumulated
        float (*partial)[K_N][PCOLS] = (float (*)[K_N][PCOLS])smem;          // [4][16][64]
        float* me_s = (float*)(smem + 4 * K_N * PCOLS * sizeof(float));      // [16][64]
        const int tile = b / NSEG, seg = b - tile * NSEG;
        const float* W; const float* bias; float* out; int ld; int j0;
        if (tile < NT_O) { W = Wo; bias = bo; out = proj_obj;   ld = DO; j0 = tile * PCOLS; }
        else             { W = Wf; bias = bf; out = proj_frame; ld = DM; j0 = (tile - NT_O) * PCOLS; }
        const int d0 = seg * DSEG;

        // stage me[:, d0:d0+64] -> LDS (coalesced, 4 elems/thread)
        for (int i = tid; i < K_N * DSEG; i += 256) {
            int k = i >> 6, dd = i & 63;
            me_s[i] = me[k * DM + d0 + dd];
        }
        __syncthreads();

        const int jj = tid & (PCOLS - 1);
        const int s  = tid >> 6;            // wave id 0..3
        const int j  = j0 + jj;
        const int db = s * 16;              // this wave's 16 d's within the segment

        float acc[K_N];
        #pragma unroll
        for (int k = 0; k < K_N; ++k) acc[k] = 0.f;

        #pragma unroll
        for (int dd = 0; dd < 16; ++dd) {
            float w = W[(size_t)(d0 + db + dd) * ld + j];      // coalesced, streams W once
            #pragma unroll
            for (int k = 0; k < K_N; ++k)
                acc[k] += me_s[k * DSEG + db + dd] * w;        // LDS broadcast
        }
        #pragma unroll
        for (int k = 0; k < K_N; ++k) partial[s][k][jj] = acc[k];
        __syncthreads();

        // cross-wave reduce + atomic accumulate (bias folded into last segment)
        for (int o = tid; o < K_N * PCOLS; o += 256) {
            int k = o >> 6, c = o & 63;
            float v = partial[0][k][c] + partial[1][k][c]
                    + partial[2][k][c] + partial[3][k][c];
            if (seg == NSEG - 1) v += bias[j0 + c];
            atomicAdd(&out[k * ld + j0 + c], v);
        }
    } else {
        // ---- histogram: per-thread private bins, 4 sub-blocks per frame
        int* bins = (int*)smem;                                  // 256*17 ints
        int (*partial2)[17] = (int (*)[17])(smem + 256 * 17 * 4);
        const int hb = b - NB_PROJ;
        const int t = hb >> 2, sub = hb & 3;
        int* my = &bins[tid * 17];
        #pragma unroll
        for (int i = 0; i < 17; ++i) my[i] = 0;

        const int4* p = (const int4*)(masks + (size_t)t * HW_N);
        const int n4 = HW_N / 4;          // 12544
        const int chunk = n4 / SUBB;      // 3136
        const int end = (sub + 1) * chunk;
        for (int i = sub * chunk + tid; i < end; i += 256) {
            int4 v = p[i];
            my[v.x]++; my[v.y]++; my[v.z]++; my[v.w]++;
        }
        __syncthreads();
        const int bcol = tid & 15, rg = tid >> 4;
        int ssum = 0;
        #pragma unroll
        for (int r = 0; r < 16; ++r) ssum += bins[(rg * 16 + r) * 17 + (bcol + 1)];
        partial2[rg][bcol] = ssum;
        __syncthreads();
        if (tid < 16) {
            int s = 0;
            #pragma unroll
            for (int r = 0; r < 16; ++r) s += partial2[r][tid];
            counts_partial[((size_t)sub * T_N + t) * K_N + tid] = (float)s;
        }
    }
}

// ============ Kernel B: obj injection blocks [0..16383] + frame blocks [16384..16639]
__global__ __launch_bounds__(256) void fusedB(const float* __restrict__ obj_feat,
                                              const int* __restrict__ obj_entity,
                                              const float* __restrict__ proj_obj,
                                              const float* __restrict__ frame_feat,
                                              const float* __restrict__ counts_partial,
                                              const float* __restrict__ proj_frame,
                                              const float* __restrict__ gamma,
                                              float* __restrict__ obj_out,
                                              float* __restrict__ frame_out) {
    __shared__ float c[K_N];
    const int b = blockIdx.x;
    const float g = gamma[0];

    if (b < T_N * O_N) {
        // ---- obj: one block per (t,o) row of 2048 floats
        const int row = b;
        const int e = obj_entity[row];              // scalar broadcast
        const float4* src = (const float4*)(obj_feat + (size_t)row * DO);
        float4* dst = (float4*)(obj_out + (size_t)row * DO);
        const int n4 = DO / 4;                      // 512
        if (e > 0) {
            const float4* pr = (const float4*)(proj_obj + (size_t)(e - 1) * DO);
            for (int i = threadIdx.x; i < n4; i += 256) {
                float4 a = src[i];
                float4 p = pr[i];
                dst[i] = make_float4(a.x + g * p.x, a.y + g * p.y,
                                     a.z + g * p.z, a.w + g * p.w);
            }
        } else {
            for (int i = threadIdx.x; i < n4; i += 256) dst[i] = src[i];
        }
    } else {
        // ---- frame: one block per frame t
        const int t = b - T_N * O_N;
        if (threadIdx.x < K_N) {
            float s = 0.f;
            #pragma unroll
            for (int sb = 0; sb < SUBB; ++sb)
                s += counts_partial[((size_t)sb * T_N + t) * K_N + threadIdx.x];
            c[threadIdx.x] = s;
        }
        __syncthreads();
        float tot = 0.f;
        #pragma unroll
        for (int k = 0; k < K_N; ++k) tot += c[k];
        const float inv = g / (OMEGA_F + tot);
        for (int j = threadIdx.x; j < DM; j += 256) {
            float acc = 0.f;
            #pragma unroll
            for (int k = 0; k < K_N; ++k) acc += c[k] * proj_frame[k * DM + j];
            frame_out[t * DM + j] = frame_feat[t * DM + j] + acc * inv;
        }
    }
}

extern "C" void kernel_launch(void* const* d_in, const int* in_sizes, int n_in,
                              void* d_out, int out_size, void* d_ws, size_t ws_size,
                              hipStream_t stream) {
    const float* obj_feat   = (const float*)d_in[0];   // [T,O,DO]
    const float* frame_feat = (const float*)d_in[1];   // [T,DM]
    const float* me         = (const float*)d_in[2];   // [K,DM]
    const int*   obj_entity = (const int*)d_in[3];     // [T,O]
    const int*   masks      = (const int*)d_in[4];     // [T,H,W]
    const float* Wo         = (const float*)d_in[5];   // [DM,DO]
    const float* bo         = (const float*)d_in[6];   // [DO]
    const float* Wf         = (const float*)d_in[7];   // [DM,DM]
    const float* bf         = (const float*)d_in[8];   // [DM]
    const float* gamma      = (const float*)d_in[9];   // scalar

    float* obj_out   = (float*)d_out;                          // [T,O,DO]
    float* frame_out = (float*)d_out + (size_t)T_N * O_N * DO; // [T,DM]

    float* ws = (float*)d_ws;
    float* proj_obj       = ws;                  // 16*2048 = 32768 floats
    float* proj_frame     = ws + 32768;          // 16*768  = 12288 floats
    float* counts_partial = ws + 32768 + 12288;  // 4*256*16 = 16384 floats

    // zero the atomic split-K accumulators (capture-legal memset node)
    hipMemsetAsync(ws, 0, (size_t)(32768 + 12288) * sizeof(float), stream);

    fusedA<<<NB_PROJ + NB_HIST, 256, 0, stream>>>(
        me, Wo, bo, Wf, bf, masks, proj_obj, proj_frame, counts_partial);
    fusedB<<<T_N * O_N + T_N, 256, 0, stream>>>(
        obj_feat, obj_entity, proj_obj, frame_feat, counts_partial, proj_frame,
        gamma, obj_out, frame_out);
}